// Round 1
// baseline (61562.061 us; speedup 1.0000x reference)
//
#include <hip/hip_runtime.h>
#include <math.h>

// Problem constants (from reference)
#define B_ 2
#define T_ 2048
#define D_ 1024
#define H_ 16
#define HD_ 64
#define L_ 8
#define DI_ 2048
#define VOCAB_ 32000
#define M_ (B_ * T_)          // 4096 rows
#define EPS_ 1e-6f

// ---------------------------------------------------------------------------
// Embedding gather: x[row, :] = emb[idx[row], :]
// grid = M_, block = 256 (each thread one float4; D/4 = 256)
// ---------------------------------------------------------------------------
__global__ __launch_bounds__(256) void embed_kernel(
    const int* __restrict__ idx, const float* __restrict__ emb,
    float* __restrict__ x) {
  int row = blockIdx.x;
  int tok = idx[row];
  const float4* src = (const float4*)(emb + (size_t)tok * D_);
  float4* dst = (float4*)(x + (size_t)row * D_);
  dst[threadIdx.x] = src[threadIdx.x];
}

// ---------------------------------------------------------------------------
// RMSNorm: out[row,:] = x[row,:] * rsqrt(mean(x^2)+eps) * w
// grid = M_, block = 256 (each thread one float4)
// ---------------------------------------------------------------------------
__global__ __launch_bounds__(256) void rmsnorm_kernel(
    const float* __restrict__ x, const float* __restrict__ w,
    float* __restrict__ out) {
  int row = blockIdx.x;
  const float4* xr = (const float4*)(x + (size_t)row * D_);
  float4 v = xr[threadIdx.x];
  float ss = v.x * v.x + v.y * v.y + v.z * v.z + v.w * v.w;
  #pragma unroll
  for (int off = 32; off; off >>= 1) ss += __shfl_xor(ss, off, 64);
  __shared__ float red[4];
  int wid = threadIdx.x >> 6;
  if ((threadIdx.x & 63) == 0) red[wid] = ss;
  __syncthreads();
  float tot = red[0] + red[1] + red[2] + red[3];
  float rms = rsqrtf(tot * (1.0f / D_) + EPS_);
  float4 wv = ((const float4*)w)[threadIdx.x];
  float4 o;
  o.x = v.x * rms * wv.x;
  o.y = v.y * rms * wv.y;
  o.z = v.z * rms * wv.z;
  o.w = v.w * rms * wv.w;
  ((float4*)(out + (size_t)row * D_))[threadIdx.x] = o;
}

// ---------------------------------------------------------------------------
// Tiled fp32 GEMM:  C[M,N] = A[M,K] @ W[N,K]^T   (all dims % 64 == 0, K % 16)
// mode 0: C = acc      mode 1: C = R + acc (residual add)
// 64x64 tile, 256 threads, 4x4 per-thread microkernel, K-tile = 16.
// LDS pad to 17 floats -> 2-way bank aliasing (free on gfx950, m136).
// ---------------------------------------------------------------------------
#define TS 64
#define KT 16
__global__ __launch_bounds__(256) void gemm_bt(
    const float* __restrict__ A, const float* __restrict__ W,
    float* __restrict__ C, const float* __restrict__ R,
    int N, int K, int mode) {
  __shared__ float As[TS][KT + 1];
  __shared__ float Ws[TS][KT + 1];
  int tid = threadIdx.x;
  int tx = tid & 15, ty = tid >> 4;
  int row0 = blockIdx.y * TS;
  int col0 = blockIdx.x * TS;
  int lr = tid >> 2;         // staging row 0..63
  int lc = (tid & 3) * 4;    // staging col {0,4,8,12}
  float acc[4][4] = {};

  for (int kt = 0; kt < K; kt += KT) {
    float4 av = *(const float4*)(A + (size_t)(row0 + lr) * K + kt + lc);
    float4 wv = *(const float4*)(W + (size_t)(col0 + lr) * K + kt + lc);
    As[lr][lc + 0] = av.x; As[lr][lc + 1] = av.y;
    As[lr][lc + 2] = av.z; As[lr][lc + 3] = av.w;
    Ws[lr][lc + 0] = wv.x; Ws[lr][lc + 1] = wv.y;
    Ws[lr][lc + 2] = wv.z; Ws[lr][lc + 3] = wv.w;
    __syncthreads();
    #pragma unroll
    for (int k = 0; k < KT; ++k) {
      float a0 = As[ty * 4 + 0][k], a1 = As[ty * 4 + 1][k];
      float a2 = As[ty * 4 + 2][k], a3 = As[ty * 4 + 3][k];
      float b0 = Ws[tx * 4 + 0][k], b1 = Ws[tx * 4 + 1][k];
      float b2 = Ws[tx * 4 + 2][k], b3 = Ws[tx * 4 + 3][k];
      acc[0][0] += a0 * b0; acc[0][1] += a0 * b1; acc[0][2] += a0 * b2; acc[0][3] += a0 * b3;
      acc[1][0] += a1 * b0; acc[1][1] += a1 * b1; acc[1][2] += a1 * b2; acc[1][3] += a1 * b3;
      acc[2][0] += a2 * b0; acc[2][1] += a2 * b1; acc[2][2] += a2 * b2; acc[2][3] += a2 * b3;
      acc[3][0] += a3 * b0; acc[3][1] += a3 * b1; acc[3][2] += a3 * b2; acc[3][3] += a3 * b3;
    }
    __syncthreads();
  }

  #pragma unroll
  for (int i = 0; i < 4; ++i) {
    size_t ro = (size_t)(row0 + ty * 4 + i) * N + col0 + tx * 4;
    if (mode == 1) {
      #pragma unroll
      for (int j = 0; j < 4; ++j) C[ro + j] = R[ro + j] + acc[i][j];
    } else {
      #pragma unroll
      for (int j = 0; j < 4; ++j) C[ro + j] = acc[i][j];
    }
  }
}

// ---------------------------------------------------------------------------
// Causal attention, online softmax. One wave (64 lanes) per (b, h, q) row.
// lane = head-dim index (HD == 64). qkv layout: [M, 3, H, HD] flattened.
// ---------------------------------------------------------------------------
__global__ __launch_bounds__(64) void attn_kernel(
    const float* __restrict__ qkv, float* __restrict__ y) {
  int gid = blockIdx.x;            // b*H*T + h*T + q
  int q = gid % T_;
  int h = (gid / T_) % H_;
  int b = gid / (T_ * H_);
  int lane = threadIdx.x;
  const float scale = 0.125f;      // 1/sqrt(64)

  const float* qp = qkv + ((size_t)(b * T_ + q)) * 3 * D_ + h * HD_ + lane;
  float qv = qp[0] * scale;
  const float* kbase = qkv + (size_t)b * T_ * 3 * D_ + D_ + h * HD_ + lane;
  const float* vbase = kbase + D_;

  float m = -INFINITY, l = 0.f, acc = 0.f;
  for (int k = 0; k <= q; ++k) {
    float kv = kbase[(size_t)k * 3 * D_];
    float s = qv * kv;
    #pragma unroll
    for (int off = 32; off; off >>= 1) s += __shfl_xor(s, off, 64);
    float vv = vbase[(size_t)k * 3 * D_];
    float newm = fmaxf(m, s);
    float alpha = __expf(m - newm);   // exp(-inf)=0 handles first iter
    float p = __expf(s - newm);
    l = l * alpha + p;
    acc = acc * alpha + p * vv;
    m = newm;
  }
  y[((size_t)(b * T_ + q)) * D_ + h * HD_ + lane] = acc / l;
}

// ---------------------------------------------------------------------------
// FFN elementwise: g = silu(g) * u
// ---------------------------------------------------------------------------
__global__ __launch_bounds__(256) void silu_mul_kernel(
    float* __restrict__ g, const float* __restrict__ u, size_t n) {
  size_t i = (size_t)blockIdx.x * 256 + threadIdx.x;
  if (i < n) {
    float gv = g[i];
    float s = gv / (1.0f + __expf(-gv));
    g[i] = s * u[i];
  }
}

// ---------------------------------------------------------------------------
extern "C" void kernel_launch(void* const* d_in, const int* in_sizes, int n_in,
                              void* d_out, int out_size, void* d_ws,
                              size_t ws_size, hipStream_t stream) {
  const int* idx = (const int*)d_in[0];
  const float* emb = (const float*)d_in[1];
  const float* ln1 = (const float*)d_in[2];
  const float* qkvw = (const float*)d_in[3];
  const float* ow = (const float*)d_in[4];
  const float* ln2 = (const float*)d_in[5];
  const float* gw = (const float*)d_in[6];
  const float* uw = (const float*)d_in[7];
  const float* dw = (const float*)d_in[8];
  const float* lnf = (const float*)d_in[9];
  float* out = (float*)d_out;

  float* ws = (float*)d_ws;
  float* x    = ws;                               // M*D
  float* h    = x + (size_t)M_ * D_;              // M*D
  float* qkv  = h + (size_t)M_ * D_;              // M*3D
  float* gate = qkv + (size_t)M_ * 3 * D_;        // M*DI
  float* up   = gate + (size_t)M_ * DI_;          // M*DI

  embed_kernel<<<M_, 256, 0, stream>>>(idx, emb, x);

  for (int l = 0; l < L_; ++l) {
    // h = rmsnorm(x, ln1)
    rmsnorm_kernel<<<M_, 256, 0, stream>>>(x, ln1 + (size_t)l * D_, h);
    // qkv = h @ qkv_w^T
    gemm_bt<<<dim3(3 * D_ / TS, M_ / TS), 256, 0, stream>>>(
        h, qkvw + (size_t)l * 3 * D_ * D_, qkv, nullptr, 3 * D_, D_, 0);
    // attention -> reuse h as y
    attn_kernel<<<B_ * H_ * T_, 64, 0, stream>>>(qkv, h);
    // x = x + y @ o_w^T
    gemm_bt<<<dim3(D_ / TS, M_ / TS), 256, 0, stream>>>(
        h, ow + (size_t)l * D_ * D_, x, x, D_, D_, 1);
    // h = rmsnorm(x, ln2)
    rmsnorm_kernel<<<M_, 256, 0, stream>>>(x, ln2 + (size_t)l * D_, h);
    // gate = h @ gate_w^T ; up = h @ up_w^T
    gemm_bt<<<dim3(DI_ / TS, M_ / TS), 256, 0, stream>>>(
        h, gw + (size_t)l * DI_ * D_, gate, nullptr, DI_, D_, 0);
    gemm_bt<<<dim3(DI_ / TS, M_ / TS), 256, 0, stream>>>(
        h, uw + (size_t)l * DI_ * D_, up, nullptr, DI_, D_, 0);
    // gate = silu(gate) * up
    size_t n = (size_t)M_ * DI_;
    silu_mul_kernel<<<(unsigned)((n + 255) / 256), 256, 0, stream>>>(gate, up, n);
    // x = x + gate @ down_w^T
    gemm_bt<<<dim3(D_ / TS, M_ / TS), 256, 0, stream>>>(
        gate, dw + (size_t)l * D_ * DI_, x, x, D_, DI_, 1);
  }

  // final norm + logits
  rmsnorm_kernel<<<M_, 256, 0, stream>>>(x, lnf, h);
  gemm_bt<<<dim3(VOCAB_ / TS, M_ / TS), 256, 0, stream>>>(
      h, emb, out, nullptr, VOCAB_, D_, 0);
}